// Round 3
// baseline (538.734 us; speedup 1.0000x reference)
//
#include <hip/hip_runtime.h>

// Confirmed device layout (evidence: R1 finite-error w/ int64 idx, R2 NaN w/ bf16):
//   x:       float32 [BATCH, IN_DIM]   (4096 x 16384)
//   weights: float32 [OUT_DIM, 16]
//   a_idx:   int32   [OUT_DIM]
//   b_idx:   int32   [OUT_DIM]
//   out:     float32 [BATCH, OUT_DIM]
// out[r,c] = k0 + k1*a + k2*b + k3*a*b, a = x[r,a_idx[c]], b = x[r,b_idx[c]],
// k[c] = softmax(weights[c,:]) @ GATE_COEFFS (16x4).

__device__ __constant__ float GC[16][4] = {
    {0.f, 0.f, 0.f, 0.f},  {0.f, 0.f, 0.f, 1.f},
    {0.f, 1.f, 0.f, -1.f}, {0.f, 1.f, 0.f, 0.f},
    {0.f, 0.f, 1.f, -1.f}, {0.f, 0.f, 1.f, 0.f},
    {0.f, 1.f, 1.f, -2.f}, {0.f, 1.f, 1.f, -1.f},
    {1.f, -1.f, -1.f, 1.f},{1.f, -1.f, -1.f, 2.f},
    {1.f, 0.f, -1.f, 0.f}, {1.f, 0.f, -1.f, 1.f},
    {1.f, -1.f, 0.f, 0.f}, {1.f, -1.f, 0.f, 1.f},
    {1.f, 0.f, 0.f, -1.f}, {1.f, 0.f, 0.f, 0.f}};

// ---- meta: per-column k (float4) + indices (int2) into d_ws ----
__global__ void meta_kernel(const float* __restrict__ weights,
                            const int* __restrict__ a_idx,
                            const int* __restrict__ b_idx,
                            float4* __restrict__ k_out,
                            int2* __restrict__ idx_out, int out_dim) {
    int c = blockIdx.x * blockDim.x + threadIdx.x;
    if (c >= out_dim) return;
    const float4* wr = (const float4*)(weights + (size_t)c * 16);
    float4 q0 = wr[0], q1 = wr[1], q2 = wr[2], q3 = wr[3];
    float w[16] = {q0.x, q0.y, q0.z, q0.w, q1.x, q1.y, q1.z, q1.w,
                   q2.x, q2.y, q2.z, q2.w, q3.x, q3.y, q3.z, q3.w};
    float m = w[0];
#pragma unroll
    for (int i = 1; i < 16; ++i) m = fmaxf(m, w[i]);
    float S = 0.f, s0 = 0.f, s1 = 0.f, s2 = 0.f, s3 = 0.f;
#pragma unroll
    for (int i = 0; i < 16; ++i) {
        float e = expf(w[i] - m);
        S += e;
        s0 = fmaf(e, GC[i][0], s0);
        s1 = fmaf(e, GC[i][1], s1);
        s2 = fmaf(e, GC[i][2], s2);
        s3 = fmaf(e, GC[i][3], s3);
    }
    float inv = 1.f / S;
    k_out[c] = make_float4(s0 * inv, s1 * inv, s2 * inv, s3 * inv);
    idx_out[c] = make_int2(a_idx[c], b_idx[c]);
}

// ---- main: one row per block staged in LDS; gather from LDS; float4 stores ----
__global__ __launch_bounds__(512) void logic_main_kernel(
    const float* __restrict__ x, const float4* __restrict__ k_meta,
    const int2* __restrict__ idx_meta, float* __restrict__ out,
    int in_dim, int out_dim) {
    __shared__ float rowbuf[16384];  // 64 KiB: one full fp32 x-row
    const int row = blockIdx.x;
    const float4* src = (const float4*)(x + (size_t)row * in_dim);
    float4* dst = (float4*)rowbuf;
    const int n4in = in_dim >> 2;
    for (int i = threadIdx.x; i < n4in; i += 512) dst[i] = src[i];
    __syncthreads();

    float4* orow = (float4*)(out + (size_t)row * out_dim);
    const int n4out = out_dim >> 2;
    for (int q = threadIdx.x; q < n4out; q += 512) {
        const int c = q << 2;
        int2 ab0 = idx_meta[c + 0];
        int2 ab1 = idx_meta[c + 1];
        int2 ab2 = idx_meta[c + 2];
        int2 ab3 = idx_meta[c + 3];
        float4 k0 = k_meta[c + 0];
        float4 k1 = k_meta[c + 1];
        float4 k2 = k_meta[c + 2];
        float4 k3 = k_meta[c + 3];
        float a0 = rowbuf[ab0.x], b0 = rowbuf[ab0.y];
        float a1 = rowbuf[ab1.x], b1 = rowbuf[ab1.y];
        float a2 = rowbuf[ab2.x], b2 = rowbuf[ab2.y];
        float a3 = rowbuf[ab3.x], b3 = rowbuf[ab3.y];
        float4 r;
        r.x = fmaf(k0.w, a0 * b0, fmaf(k0.z, b0, fmaf(k0.y, a0, k0.x)));
        r.y = fmaf(k1.w, a1 * b1, fmaf(k1.z, b1, fmaf(k1.y, a1, k1.x)));
        r.z = fmaf(k2.w, a2 * b2, fmaf(k2.z, b2, fmaf(k2.y, a2, k2.x)));
        r.w = fmaf(k3.w, a3 * b3, fmaf(k3.z, b3, fmaf(k3.y, a3, k3.x)));
        orow[q] = r;
    }
}

// ---- fallback: fused, slow but correct (only if ws too small) ----
__global__ void fallback_kernel(const float* __restrict__ x,
                                const float* __restrict__ weights,
                                const int* __restrict__ a_idx,
                                const int* __restrict__ b_idx,
                                float* __restrict__ out, long long total,
                                int in_dim, int out_dim) {
    long long stride = (long long)gridDim.x * blockDim.x;
    for (long long t = (long long)blockIdx.x * blockDim.x + threadIdx.x;
         t < total; t += stride) {
        int c = (int)(t % out_dim);
        long long row = t / out_dim;
        const float* wr = weights + (size_t)c * 16;
        float m = wr[0];
#pragma unroll
        for (int i = 1; i < 16; ++i) m = fmaxf(m, wr[i]);
        float S = 0.f, s0 = 0.f, s1 = 0.f, s2 = 0.f, s3 = 0.f;
#pragma unroll
        for (int i = 0; i < 16; ++i) {
            float e = expf(wr[i] - m);
            S += e;
            s0 = fmaf(e, GC[i][0], s0);
            s1 = fmaf(e, GC[i][1], s1);
            s2 = fmaf(e, GC[i][2], s2);
            s3 = fmaf(e, GC[i][3], s3);
        }
        float inv = 1.f / S;
        float a = x[row * (size_t)in_dim + a_idx[c]];
        float b = x[row * (size_t)in_dim + b_idx[c]];
        out[t] = fmaf(s3 * inv, a * b,
                      fmaf(s2 * inv, b, fmaf(s1 * inv, a, s0 * inv)));
    }
}

extern "C" void kernel_launch(void* const* d_in, const int* in_sizes, int n_in,
                              void* d_out, int out_size, void* d_ws,
                              size_t ws_size, hipStream_t stream) {
    const float* x = (const float*)d_in[0];
    const float* weights = (const float*)d_in[1];
    const int* a_idx = (const int*)d_in[2];
    const int* b_idx = (const int*)d_in[3];
    float* out = (float*)d_out;

    const int out_dim = in_sizes[2];        // 16384
    const int batch = out_size / out_dim;   // 4096
    const int in_dim = in_sizes[0] / batch; // 16384

    const size_t k_bytes = (size_t)out_dim * sizeof(float4);
    const size_t idx_bytes = (size_t)out_dim * sizeof(int2);

    const bool ok = ws_size >= k_bytes + idx_bytes && in_dim <= 16384 &&
                    (in_dim % 4) == 0 && (out_dim % 4) == 0;
    if (ok) {
        float4* k_meta = (float4*)d_ws;
        int2* idx_meta = (int2*)((char*)d_ws + k_bytes);
        meta_kernel<<<(out_dim + 255) / 256, 256, 0, stream>>>(
            weights, a_idx, b_idx, k_meta, idx_meta, out_dim);
        logic_main_kernel<<<batch, 512, 0, stream>>>(x, k_meta, idx_meta, out,
                                                     in_dim, out_dim);
    } else {
        long long total = (long long)batch * out_dim;
        fallback_kernel<<<4096, 256, 0, stream>>>(x, weights, a_idx, b_idx,
                                                  out, total, in_dim, out_dim);
    }
}